// Round 2
// baseline (407.558 us; speedup 1.0000x reference)
//
#include <hip/hip_runtime.h>
#include <stddef.h>
#include <stdint.h>

// ---------- problem dims (fixed by setup_inputs) ----------
#define BDIM 2
#define SDIM 2048
#define DDIM 1024
#define FDIM 4096
#define ENUM 8
#define KSEL 2
#define TTOK (BDIM * SDIM)        // 4096 tokens
#define PPAIR (TTOK * KSEL)       // 8192 (token,k) pairs
#define VOUT ((size_t)TTOK * DDIM) // 4194304 floats of "mixed"
#define MBMAX 72                  // max m-blocks: sum ceil(cnt_e/128) <= 64+7

typedef float f32x4 __attribute__((ext_vector_type(4)));
typedef short bf16x8 __attribute__((ext_vector_type(8)));
typedef unsigned short u16x8 __attribute__((ext_vector_type(8)));
typedef unsigned short u16x4 __attribute__((ext_vector_type(4)));

__device__ __forceinline__ unsigned short f2bf(float f) {
  unsigned int u = __float_as_uint(f);
  u += 0x7fffu + ((u >> 16) & 1u);   // RNE
  return (unsigned short)(u >> 16);
}

__device__ __forceinline__ float gelu_tanh(float x) {
  float u = 0.7978845608028654f * (x + 0.044715f * x * x * x);
  float e = __expf(2.0f * u);
  float t = 1.0f - 2.0f / (e + 1.0f);   // tanh(u), safe at +-inf
  return 0.5f * x * (1.0f + t);
}

__device__ __forceinline__ void gload16(const void* g, void* l) {
  __builtin_amdgcn_global_load_lds(
      (const __attribute__((address_space(1))) unsigned int*)g,
      (__attribute__((address_space(3))) unsigned int*)l, 16, 0, 0);
}

// ---------- kernel 1: router stats ----------
__global__ __launch_bounds__(256) void stats_kernel(const float* __restrict__ lg,
                                                    float* __restrict__ out) {
  __shared__ float se[256], sm[256];
  float ent = 0.f, mar = 0.f;
  for (int r = threadIdx.x; r < TTOK; r += 256) {
    float v[ENUM];
    float mx = -1e30f;
#pragma unroll
    for (int i = 0; i < ENUM; ++i) { v[i] = lg[r * ENUM + i]; mx = fmaxf(mx, v[i]); }
    float s = 0.f;
#pragma unroll
    for (int i = 0; i < ENUM; ++i) { v[i] = __expf(v[i] - mx); s += v[i]; }
    float inv = 1.f / s;
    float p1 = -1.f, p2 = -1.f, e_ = 0.f;
#pragma unroll
    for (int i = 0; i < ENUM; ++i) {
      float p = v[i] * inv;
      e_ -= p * logf(fmaxf(p, 1e-9f));
      if (p > p1) { p2 = p1; p1 = p; } else if (p > p2) { p2 = p; }
    }
    ent += e_; mar += (p1 - p2);
  }
  se[threadIdx.x] = ent; sm[threadIdx.x] = mar;
  __syncthreads();
  for (int s = 128; s > 0; s >>= 1) {
    if (threadIdx.x < (unsigned)s) { se[threadIdx.x] += se[threadIdx.x + s]; sm[threadIdx.x] += sm[threadIdx.x + s]; }
    __syncthreads();
  }
  if (threadIdx.x == 0) {
    out[VOUT]     = se[0] / (float)TTOK;
    out[VOUT + 1] = sm[0] / (float)TTOK;
  }
}

// ---------- kernel 2: routing (group pairs by expert; build m-block table + inverse map) ----------
__global__ __launch_bounds__(256) void routing_kernel(const int* __restrict__ eidx,
                                                      int* __restrict__ g_cnt,
                                                      int* __restrict__ g_off,
                                                      int* __restrict__ pairTok,
                                                      int* __restrict__ inv,
                                                      int* __restrict__ blkE,
                                                      int* __restrict__ blkM,
                                                      int* __restrict__ nMB) {
  __shared__ int sc[ENUM], so[ENUM], scur[ENUM];
  const int tid = threadIdx.x;
  if (tid < ENUM) sc[tid] = 0;
  __syncthreads();
  for (int p = tid; p < PPAIR; p += 256) atomicAdd(&sc[eidx[p]], 1);
  __syncthreads();
  if (tid == 0) {
    int o = 0, nb = 0;
    for (int e = 0; e < ENUM; ++e) {
      so[e] = o;
      for (int m0 = 0; m0 < sc[e]; m0 += 128) { blkE[nb] = e; blkM[nb] = m0; ++nb; }
      o += sc[e];
    }
    nMB[0] = nb;
  }
  __syncthreads();
  if (tid < ENUM) { scur[tid] = so[tid]; g_cnt[tid] = sc[tid]; g_off[tid] = so[tid]; }
  __syncthreads();
  for (int p = tid; p < PPAIR; p += 256) {
    int e = eidx[p];
    int pos = atomicAdd(&scur[e], 1);
    pairTok[pos] = p >> 1;  // token id
    inv[p] = pos;           // grouped position of pair p
  }
}

// ---------- kernel 3: hidden fp32 -> bf16 ----------
__global__ __launch_bounds__(256) void cvt_hidden_kernel(const float* __restrict__ in,
                                                         unsigned short* __restrict__ outp) {
  const int i = blockIdx.x * 256 + threadIdx.x;
  f32x4 a = ((const f32x4*)in)[(size_t)i * 2];
  f32x4 b = ((const f32x4*)in)[(size_t)i * 2 + 1];
  u16x8 o;
  o[0] = f2bf(a[0]); o[1] = f2bf(a[1]); o[2] = f2bf(a[2]); o[3] = f2bf(a[3]);
  o[4] = f2bf(b[0]); o[5] = f2bf(b[1]); o[6] = f2bf(b[2]); o[7] = f2bf(b[3]);
  ((u16x8*)outp)[i] = o;
}

// ---------- kernel 4: transpose + convert: fp32 [R][C] -> bf16 [C][R] per expert z ----------
__global__ __launch_bounds__(256) void transpose_cvt_kernel(const float* __restrict__ in,
                                                            unsigned short* __restrict__ outp,
                                                            int R, int C) {
  __shared__ float tile[32][33];
  const size_t base = (size_t)blockIdx.z * (size_t)R * (size_t)C;
  const float* ip = in + base;
  unsigned short* op = outp + base;
  const int r0 = blockIdx.y * 32, c0 = blockIdx.x * 32;
  const int i = threadIdx.x >> 3;
  const int j4 = (threadIdx.x & 7) << 2;
  f32x4 v = *(const f32x4*)(ip + (size_t)(r0 + i) * C + c0 + j4);
  tile[i][j4 + 0] = v[0]; tile[i][j4 + 1] = v[1]; tile[i][j4 + 2] = v[2]; tile[i][j4 + 3] = v[3];
  __syncthreads();
  u16x4 o;
  o[0] = f2bf(tile[j4 + 0][i]); o[1] = f2bf(tile[j4 + 1][i]);
  o[2] = f2bf(tile[j4 + 2][i]); o[3] = f2bf(tile[j4 + 3][i]);
  *(u16x4*)(op + (size_t)(c0 + i) * R + r0 + j4) = o;
}

// ---------- grouped GEMM 1: h1 = gelu(hB[tok] @ w1T[e]^T + b1[e]) ----------
// grid (MBMAX, 32); work-id swizzled: m fastest (shares B-tile), chunked per XCD
__global__ __launch_bounds__(256) void gemm1_kernel(const unsigned short* __restrict__ hB,   // [T][D]
                                                    const unsigned short* __restrict__ w1T,  // [E][F][D]
                                                    const float* __restrict__ b1,            // [E][F]
                                                    const int* __restrict__ g_cnt,
                                                    const int* __restrict__ g_off,
                                                    const int* __restrict__ pairTok,
                                                    const int* __restrict__ blkE,
                                                    const int* __restrict__ blkM,
                                                    const int* __restrict__ nMB,
                                                    unsigned short* __restrict__ h1) {       // [P][F]
  const int flat = blockIdx.x + MBMAX * blockIdx.y;     // 0..2303, 2304%8==0
  const int w = (flat & 7) * (MBMAX * 32 / 8) + (flat >> 3);  // chunked XCD swizzle
  const int mI = w % MBMAX;
  const int nB = w / MBMAX;
  if (mI >= nMB[0]) return;
  const int e = blkE[mI];
  const int m0 = blkM[mI];
  const int cnt_e = g_cnt[e];
  const int off_e = g_off[e];
  const int rows_e = min(128, cnt_e - m0);
  const int n0 = nB << 7;

  __shared__ __align__(16) unsigned short As[2][128 * 32];
  __shared__ __align__(16) unsigned short Bs[2][128 * 32];

  const int tid = threadIdx.x;
  const int lane = tid & 63;
  const int wid = tid >> 6;
  const int wr = wid >> 1, wc = wid & 1;

  const int l2 = lane >> 2;
  const int sg = (lane & 3) ^ ((lane >> 3) & 3);
  const unsigned short* gA[2];
  const unsigned short* gB[2];
  int ldsOff[2];
#pragma unroll
  for (int c = 0; c < 2; ++c) {
    const int reg = wid * 2 + c;
    const int row = reg * 16 + l2;
    const int tok = pairTok[off_e + m0 + min(row, rows_e - 1)];
    gA[c] = hB + (size_t)tok * DDIM + (sg << 3);
    gB[c] = w1T + ((size_t)e * FDIM + (n0 + row)) * DDIM + (sg << 3);
    ldsOff[c] = reg * 512;
  }

  const int kh = lane >> 4;
  const int l15 = lane & 15;
  int aoff[4], boff[4];
#pragma unroll
  for (int i = 0; i < 4; ++i) {
    const int ar = wr * 64 + i * 16 + l15;
    aoff[i] = ar * 32 + ((kh ^ ((ar >> 1) & 3)) << 3);
    const int br = wc * 64 + i * 16 + l15;
    boff[i] = br * 32 + ((kh ^ ((br >> 1) & 3)) << 3);
  }

  f32x4 acc[4][4];
#pragma unroll
  for (int i = 0; i < 4; ++i)
#pragma unroll
    for (int j = 0; j < 4; ++j) acc[i][j] = (f32x4){0.f, 0.f, 0.f, 0.f};

#pragma unroll
  for (int c = 0; c < 2; ++c) {
    gload16(gA[c], &As[0][ldsOff[c]]);
    gload16(gB[c], &Bs[0][ldsOff[c]]);
  }
  __syncthreads();

  int cur = 0;
  const int KT = DDIM / 32;
  for (int kt = 0; kt < KT; ++kt) {
    if (kt + 1 < KT) {
#pragma unroll
      for (int c = 0; c < 2; ++c) {
        gload16(gA[c] + (size_t)(kt + 1) * 32, &As[cur ^ 1][ldsOff[c]]);
        gload16(gB[c] + (size_t)(kt + 1) * 32, &Bs[cur ^ 1][ldsOff[c]]);
      }
    }
    bf16x8 af[4], bfr[4];
#pragma unroll
    for (int i = 0; i < 4; ++i) af[i] = *(const bf16x8*)&As[cur][aoff[i]];
#pragma unroll
    for (int i = 0; i < 4; ++i) bfr[i] = *(const bf16x8*)&Bs[cur][boff[i]];
#pragma unroll
    for (int im = 0; im < 4; ++im)
#pragma unroll
      for (int in = 0; in < 4; ++in)
        acc[im][in] = __builtin_amdgcn_mfma_f32_16x16x32_bf16(af[im], bfr[in], acc[im][in], 0, 0, 0);
    __syncthreads();
    cur ^= 1;
  }

#pragma unroll
  for (int im = 0; im < 4; ++im) {
#pragma unroll
    for (int j = 0; j < 4; ++j) {
      const int row = wr * 64 + im * 16 + kh * 4 + j;
      if (row < rows_e) {
        unsigned short* dst = h1 + (size_t)(off_e + m0 + row) * FDIM;
#pragma unroll
        for (int in = 0; in < 4; ++in) {
          const int col = n0 + wc * 64 + in * 16 + l15;
          float x = acc[im][in][j] + b1[e * FDIM + col];
          dst[col] = f2bf(gelu_tanh(x));
        }
      }
    }
  }
}

// ---------- grouped GEMM 2 (split-K x2): h2p[s][q] = h1[q] @ w2T[e][:,sK] (+ b2 on s==0) ----------
// grid (MBMAX, 8, 2); grouped-order output (no scatter), fp32 partials
__global__ __launch_bounds__(256) void gemm2_kernel(const unsigned short* __restrict__ h1,   // [P][F]
                                                    const unsigned short* __restrict__ w2T,  // [E][D][F]
                                                    const float* __restrict__ b2,            // [E][D]
                                                    const int* __restrict__ g_cnt,
                                                    const int* __restrict__ g_off,
                                                    const int* __restrict__ blkE,
                                                    const int* __restrict__ blkM,
                                                    const int* __restrict__ nMB,
                                                    float* __restrict__ h2p) {               // [2][P][D]
  const int flat = blockIdx.x + MBMAX * blockIdx.y;     // 0..575, 576%8==0
  const int w = (flat & 7) * (MBMAX * 8 / 8) + (flat >> 3);
  const int mI = w % MBMAX;
  const int nB = w / MBMAX;
  if (mI >= nMB[0]) return;
  const int s = blockIdx.z;
  const int e = blkE[mI];
  const int m0 = blkM[mI];
  const int cnt_e = g_cnt[e];
  const int off_e = g_off[e];
  const int rows_e = min(128, cnt_e - m0);
  const int n0 = nB << 7;
  const int kbase = s * (FDIM / 2);

  __shared__ __align__(16) unsigned short As[2][128 * 32];
  __shared__ __align__(16) unsigned short Bs[2][128 * 32];

  const int tid = threadIdx.x;
  const int lane = tid & 63;
  const int wid = tid >> 6;
  const int wr = wid >> 1, wc = wid & 1;

  const int l2 = lane >> 2;
  const int sg = (lane & 3) ^ ((lane >> 3) & 3);
  const unsigned short* gA[2];
  const unsigned short* gB[2];
  int ldsOff[2];
#pragma unroll
  for (int c = 0; c < 2; ++c) {
    const int reg = wid * 2 + c;
    const int row = reg * 16 + l2;
    const int q = off_e + m0 + min(row, rows_e - 1);
    gA[c] = h1 + (size_t)q * FDIM + kbase + (sg << 3);
    gB[c] = w2T + ((size_t)e * DDIM + (n0 + row)) * FDIM + kbase + (sg << 3);
    ldsOff[c] = reg * 512;
  }

  const int kh = lane >> 4;
  const int l15 = lane & 15;
  int aoff[4], boff[4];
#pragma unroll
  for (int i = 0; i < 4; ++i) {
    const int ar = wr * 64 + i * 16 + l15;
    aoff[i] = ar * 32 + ((kh ^ ((ar >> 1) & 3)) << 3);
    const int br = wc * 64 + i * 16 + l15;
    boff[i] = br * 32 + ((kh ^ ((br >> 1) & 3)) << 3);
  }

  f32x4 acc[4][4];
#pragma unroll
  for (int i = 0; i < 4; ++i)
#pragma unroll
    for (int j = 0; j < 4; ++j) acc[i][j] = (f32x4){0.f, 0.f, 0.f, 0.f};

#pragma unroll
  for (int c = 0; c < 2; ++c) {
    gload16(gA[c], &As[0][ldsOff[c]]);
    gload16(gB[c], &Bs[0][ldsOff[c]]);
  }
  __syncthreads();

  int cur = 0;
  const int KT = (FDIM / 2) / 32;   // 64
  for (int kt = 0; kt < KT; ++kt) {
    if (kt + 1 < KT) {
#pragma unroll
      for (int c = 0; c < 2; ++c) {
        gload16(gA[c] + (size_t)(kt + 1) * 32, &As[cur ^ 1][ldsOff[c]]);
        gload16(gB[c] + (size_t)(kt + 1) * 32, &Bs[cur ^ 1][ldsOff[c]]);
      }
    }
    bf16x8 af[4], bfr[4];
#pragma unroll
    for (int i = 0; i < 4; ++i) af[i] = *(const bf16x8*)&As[cur][aoff[i]];
#pragma unroll
    for (int i = 0; i < 4; ++i) bfr[i] = *(const bf16x8*)&Bs[cur][boff[i]];
#pragma unroll
    for (int im = 0; im < 4; ++im)
#pragma unroll
      for (int in = 0; in < 4; ++in)
        acc[im][in] = __builtin_amdgcn_mfma_f32_16x16x32_bf16(af[im], bfr[in], acc[im][in], 0, 0, 0);
    __syncthreads();
    cur ^= 1;
  }

  float* outBase = h2p + (size_t)s * PPAIR * DDIM;
#pragma unroll
  for (int im = 0; im < 4; ++im) {
#pragma unroll
    for (int j = 0; j < 4; ++j) {
      const int row = wr * 64 + im * 16 + kh * 4 + j;
      if (row < rows_e) {
        float* dp = outBase + (size_t)(off_e + m0 + row) * DDIM;
#pragma unroll
        for (int in = 0; in < 4; ++in) {
          const int col = n0 + wc * 64 + in * 16 + l15;
          float v = acc[im][in][j];
          if (s == 0) v += b2[e * DDIM + col];
          dp[col] = v;
        }
      }
    }
  }
}

// ---------- combine: out[t] = sum_k ew[t,k] * (h2p[0][inv[2t+k]] + h2p[1][inv[2t+k]]) ----------
__global__ __launch_bounds__(256) void combine_kernel(const float* __restrict__ h2p,
                                                      const float* __restrict__ ew,
                                                      const int* __restrict__ inv,
                                                      float* __restrict__ out) {
  const int i = blockIdx.x * 256 + threadIdx.x;  // over TTOK*DDIM/4
  const int t = i >> 8;
  const int c = i & 255;
  const int q0 = inv[t * 2], q1 = inv[t * 2 + 1];
  const float wa = ew[t * 2], wb = ew[t * 2 + 1];
  const f32x4* p0 = (const f32x4*)h2p;
  const f32x4* p1 = (const f32x4*)(h2p + (size_t)PPAIR * DDIM);
  f32x4 r = (p0[(size_t)q0 * 256 + c] + p1[(size_t)q0 * 256 + c]) * wa
          + (p0[(size_t)q1 * 256 + c] + p1[(size_t)q1 * 256 + c]) * wb;
  ((f32x4*)out)[i] = r;
}

// ---------- launch ----------
extern "C" void kernel_launch(void* const* d_in, const int* in_sizes, int n_in,
                              void* d_out, int out_size, void* d_ws, size_t ws_size,
                              hipStream_t stream) {
  (void)in_sizes; (void)n_in; (void)out_size; (void)ws_size;
  const float* hidden = (const float*)d_in[0];
  const int*   eidx   = (const int*)d_in[1];
  const float* ew     = (const float*)d_in[2];
  const float* rlog   = (const float*)d_in[3];
  const float* w1     = (const float*)d_in[4];
  const float* b1     = (const float*)d_in[5];
  const float* w2     = (const float*)d_in[6];
  const float* b2     = (const float*)d_in[7];
  float* out = (float*)d_out;

  char* wsb = (char*)d_ws;
  const size_t SZ_W = (size_t)ENUM * DDIM * FDIM * 2;  // 64 MiB (bf16)
  unsigned short* w1T = (unsigned short*)(wsb);
  unsigned short* w2T = (unsigned short*)(wsb + SZ_W);
  unsigned short* hB  = (unsigned short*)(wsb + 2 * SZ_W);
  unsigned short* h1  = (unsigned short*)(wsb + 2 * SZ_W + (size_t)TTOK * DDIM * 2);
  int* g_cnt   = (int*)(wsb + 2 * SZ_W + (size_t)TTOK * DDIM * 2 + (size_t)PPAIR * FDIM * 2);
  int* g_off   = g_cnt + 8;
  int* pairTok = g_off + 8;
  int* inv     = pairTok + PPAIR;
  int* blkE    = inv + PPAIR;
  int* blkM    = blkE + MBMAX;
  int* nMB     = blkM + MBMAX;
  // h2p (2 x 8192 x 1024 fp32 = 64 MiB) aliases w1T exactly (dead after gemm1)
  float* h2p = (float*)wsb;

  stats_kernel<<<1, 256, 0, stream>>>(rlog, out);
  routing_kernel<<<1, 256, 0, stream>>>(eidx, g_cnt, g_off, pairTok, inv, blkE, blkM, nMB);
  cvt_hidden_kernel<<<(TTOK * DDIM / 8 + 255) / 256, 256, 0, stream>>>(hidden, hB);
  transpose_cvt_kernel<<<dim3(FDIM / 32, DDIM / 32, ENUM), 256, 0, stream>>>(w1, w1T, DDIM, FDIM);
  transpose_cvt_kernel<<<dim3(DDIM / 32, FDIM / 32, ENUM), 256, 0, stream>>>(w2, w2T, FDIM, DDIM);
  gemm1_kernel<<<dim3(MBMAX, FDIM / 128), 256, 0, stream>>>(hB, w1T, b1, g_cnt, g_off, pairTok, blkE, blkM, nMB, h1);
  gemm2_kernel<<<dim3(MBMAX, DDIM / 128, 2), 256, 0, stream>>>(h1, w2T, b2, g_cnt, g_off, blkE, blkM, nMB, h2p);
  combine_kernel<<<(TTOK * DDIM / 4) / 256, 256, 0, stream>>>(h2p, ew, inv, out);
}